// Round 1
// 616.067 us; speedup vs baseline: 1.0180x; 1.0180x over previous
//
#include <hip/hip_runtime.h>
#include <math.h>

#define N_TOK 32768
#define DIM   256
#define KCODE 4096

// ---- workspace layout (float offsets) ----
#define WS_E2      0                      // [4096]
#define WS_COUNTS  4096                   // [4096]
#define WS_LOSSP   8192                   // [256]
#define WS_SCAL    8448                   // [64]  scal[0]=bias
#define WS_CNORM   8512                   // [4096]
#define WS_IDX     12608                  // int [32768]
#define WS_EHS     307520                 // fp16 planes [2][16][8][256][32] = 4 MB
#define WS_DWT     1356096                // dwT [4096*256]

// ---- output layout (float offsets) ----
#define OUT_Q      0
#define OUT_LOSS   8388608
#define OUT_PERP   8388609
#define OUT_IDX    8388610
#define OUT_EMB    8421378

#define EH_PLANE   1048576                // halves per eh plane
#define XH_PLANE   8388608                // halves per xh plane

typedef _Float16 f16x8 __attribute__((ext_vector_type(8)));
typedef _Float16 f16x4 __attribute__((ext_vector_type(4)));
typedef float    f32x4 __attribute__((ext_vector_type(4)));

// ||e_k||^2, partials over d with atomics (e2 pre-zeroed)
__global__ void k_e2(const float* __restrict__ emb, float* __restrict__ e2)
{
    int k  = blockIdx.x * 256 + threadIdx.x;
    int d0 = blockIdx.y * 32;
    float s = 0.0f;
#pragma unroll 8
    for (int d = 0; d < 32; ++d) {
        float v = emb[(size_t)(d0 + d) * KCODE + k];
        s += v * v;
    }
    atomicAdd(&e2[k], s);
}

// x [N][D] -> split fp16 planes xh[2][N][D] (stored in d_out OUT_Q region)
__global__ void k_split_x(const float* __restrict__ x, unsigned short* __restrict__ xh)
{
    int i = (blockIdx.x * 256 + threadIdx.x) * 8;
    float4 f0 = *(const float4*)(x + i);
    float4 f1 = *(const float4*)(x + i + 4);
    float fv[8] = {f0.x, f0.y, f0.z, f0.w, f1.x, f1.y, f1.z, f1.w};
    f16x8 h1, h2;
#pragma unroll
    for (int j = 0; j < 8; ++j) {
        _Float16 a = (_Float16)fv[j];
        h1[j] = a;
        h2[j] = (_Float16)(fv[j] - (float)a);
    }
    *(f16x8*)((_Float16*)xh + i)            = h1;
    *(f16x8*)((_Float16*)xh + XH_PLANE + i) = h2;
}

// emb [D][K] -> pre-tiled split planes ehs[p][ct][ks][code&255][d&31]
__global__ void k_split_e(const float* __restrict__ emb, unsigned short* __restrict__ ehs_)
{
    __shared__ float tile[32][33];
    _Float16* ehs = (_Float16*)ehs_;
    int t  = threadIdx.x;
    int tx = t & 31, iy = t >> 5;
    int k0 = blockIdx.x * 32, d0 = blockIdx.y * 32;
#pragma unroll
    for (int j = 0; j < 4; ++j)
        tile[iy + 8 * j][tx] = emb[(size_t)(d0 + iy + 8 * j) * KCODE + k0 + tx];
    __syncthreads();
    // tile[d_off][k_off]; this thread emits code = k0+tx, d = d0 + iy*4 .. +3
    int code = k0 + tx;
    size_t base = (size_t)(((code >> 8) * 8) + (d0 >> 5)) * 8192 + (code & 255) * 32 + iy * 4;
    f16x4 h1, h2;
#pragma unroll
    for (int j = 0; j < 4; ++j) {
        float v = tile[iy * 4 + j][tx];
        _Float16 a = (_Float16)v;
        h1[j] = a;
        h2[j] = (_Float16)(v - (float)a);
    }
    *(f16x4*)(ehs + base)            = h1;
    *(f16x4*)(ehs + EH_PLANE + base) = h2;
}

// Argmin over codes via fp16x2-split MFMA.
// Block: 64 rows x full 4096 codes (16 tiles of 256; wave w owns codes w*64..+63).
// A planes in LDS (loaded once, single barrier); B fragments loaded DIRECTLY from
// global ehs (L2-resident, coalesced 1KB/instr), register DOUBLE-BUFFERED one
// ks-step ahead so the 48-MFMA cluster hides the L2/HBM latency of the next
// step's loads (vmcnt(8) instead of vmcnt(0)-style stall every step).
__global__ __launch_bounds__(256, 2)
void k_argmin(const unsigned short* __restrict__ xh_, const unsigned short* __restrict__ ehs_,
              const float* __restrict__ e2, int* __restrict__ idx_out)
{
    __shared__ __align__(16) _Float16 Ah[2][64][256];   // 64 KB; XOR-swizzled 8-elem groups

    const _Float16* xh  = (const _Float16*)xh_;
    const _Float16* ehs = (const _Float16*)ehs_;

    const int t    = threadIdx.x;
    const int lane = t & 63, w = t >> 6;
    const int lo   = lane & 15, q = lane >> 4;
    const int row0 = blockIdx.x * 64;

    // ---- prologue: stage A planes from xh (rows m and m+32) ----
    {
        int m = t >> 3, kb = (t & 7) * 32;
#pragma unroll
        for (int p = 0; p < 2; ++p)
#pragma unroll
            for (int rr = 0; rr < 2; ++rr) {
                int mm = m + 32 * rr;
                const _Float16* src = xh + (size_t)p * XH_PLANE + (size_t)(row0 + mm) * DIM + kb;
#pragma unroll
                for (int g = 0; g < 4; ++g) {
                    f16x8 h = *(const f16x8*)(src + g * 8);
                    int grp = ((kb >> 3) + g) ^ (mm & 7);
                    *(f16x8*)&Ah[p][mm][grp * 8] = h;
                }
            }
    }
    __syncthreads();   // the ONLY barrier before the epilogue

    float best[16];
    int   bidx[16];
#pragma unroll
    for (int s = 0; s < 16; ++s) { best[s] = 3.4e38f; bidx[s] = 0; }

    // B fragment base for this lane: code-within-tile crow = w*64 + nf*16 + lo, d-off q*8
    const _Float16* ehp1 = ehs + (size_t)(w * 64 + lo) * 32 + q * 8;
    const _Float16* ehp2 = ehp1 + EH_PLANE;

    // register double-buffer for B fragments; parity = ks&1 (ks fully unrolled
    // so all indices are compile-time -> stays in VGPRs, no scratch)
    f16x8 b1f[2][4], b2f[2][4];

    // prime: load B for so = 0
#pragma unroll
    for (int nf = 0; nf < 4; ++nf) {
        b1f[0][nf] = *(const f16x8*)(ehp1 + nf * 512);
        b2f[0][nf] = *(const f16x8*)(ehp2 + nf * 512);
    }

    for (int ct = 0; ct < 16; ++ct) {
        f32x4 acc[4][4];
#pragma unroll
        for (int mf = 0; mf < 4; ++mf)
#pragma unroll
            for (int nf = 0; nf < 4; ++nf) acc[mf][nf] = (f32x4)0.0f;

#pragma unroll
        for (int ks = 0; ks < 8; ++ks) {
            const int cur = ks & 1, nxt = cur ^ 1;
            const int so  = ct * 8 + ks;

            // ---- prefetch B for so+1 into the other parity buffer ----
            // (ks<7 is compile-time true for 7/8 instances; only the ks==7
            //  instance carries a uniform scalar branch on ct)
            if (ks < 7 || ct < 15) {
                const size_t po = (size_t)(so + 1) * 8192;
#pragma unroll
                for (int nf = 0; nf < 4; ++nf) {
                    b1f[nxt][nf] = *(const f16x8*)(ehp1 + po + nf * 512);
                    b2f[nxt][nf] = *(const f16x8*)(ehp2 + po + nf * 512);
                }
            }

            // ---- A fragments via LDS (conflict-free b128 via XOR swizzle) ----
            const int agrp = ((ks * 4 + q) ^ (lo & 7)) * 8;
            f16x8 a1[4], a2[4];
#pragma unroll
            for (int mf = 0; mf < 4; ++mf)
                a2[mf] = *(const f16x8*)&Ah[1][mf * 16 + lo][agrp];
#pragma unroll
            for (int mf = 0; mf < 4; ++mf)
                a1[mf] = *(const f16x8*)&Ah[0][mf * 16 + lo][agrp];

            // ---- MFMA cluster on the CURRENT buffer (loaded last iteration) ----
            __builtin_amdgcn_s_setprio(1);
#pragma unroll
            for (int nf = 0; nf < 4; ++nf) {
#pragma unroll
                for (int mf = 0; mf < 4; ++mf) {
                    acc[mf][nf] = __builtin_amdgcn_mfma_f32_16x16x32_f16(a2[mf], b1f[cur][nf], acc[mf][nf], 0, 0, 0);
                    acc[mf][nf] = __builtin_amdgcn_mfma_f32_16x16x32_f16(a1[mf], b2f[cur][nf], acc[mf][nf], 0, 0, 0);
                    acc[mf][nf] = __builtin_amdgcn_mfma_f32_16x16x32_f16(a1[mf], b1f[cur][nf], acc[mf][nf], 0, 0, 0);
                }
            }
            __builtin_amdgcn_s_setprio(0);
        }

        // fold: dist = e2 - 2*score (x^2 row-constant dropped). codes ascending in ct,nf.
#pragma unroll
        for (int nf = 0; nf < 4; ++nf) {
            int cl = w * 64 + nf * 16 + lo;
            float e2v = e2[ct * 256 + cl];
#pragma unroll
            for (int mf = 0; mf < 4; ++mf)
#pragma unroll
                for (int r = 0; r < 4; ++r) {
                    float dist = fmaf(-2.0f, acc[mf][nf][r], e2v);
                    int s = mf * 4 + r;
                    if (dist < best[s]) { best[s] = dist; bidx[s] = ct * 256 + cl; }
                }
        }
    }

    // ---- final argmin reduction (scratch overlays Ah) ----
    __syncthreads();
    float* rv = (float*)&Ah[0][0][0];                 // [64 rows][64 slots]
    int*   ri = (int*)(((char*)&Ah[0][0][0]) + 16384);
#pragma unroll
    for (int s = 0; s < 16; ++s) {
        int row = (s >> 2) * 16 + q * 4 + (s & 3);    // mf*16 + q*4 + r
        rv[row * 64 + w * 16 + lo] = best[s];
        ri[row * 64 + w * 16 + lo] = bidx[s];
    }
    __syncthreads();
    if (t < 64) {
        float bv = rv[t * 64];
        int   bi = ri[t * 64];
        for (int j = 1; j < 64; ++j) {
            float v = rv[t * 64 + j];
            int  ii = ri[t * 64 + j];
            if (v < bv || (v == bv && ii < bi)) { bv = v; bi = ii; }
        }
        idx_out[row0 + t] = bi;
    }
}

// one wave per row: quantized copy (reconstructed from planes), loss, counts, dwT, idx
__global__ void k_gather(const float* __restrict__ x, const unsigned short* __restrict__ ehs_,
                         const int* __restrict__ idx, float* __restrict__ out_q,
                         float* __restrict__ out_idxf, float* __restrict__ counts,
                         float* __restrict__ dwT, float* __restrict__ lossp)
{
    const _Float16* ehs = (const _Float16*)ehs_;
    int t = threadIdx.x;
    int lane = t & 63, w = t >> 6;
    int n = blockIdx.x * 4 + w;
    int k = idx[n];
    float4 xv = *(const float4*)&x[(size_t)n * DIM + lane * 4];
    size_t base = (size_t)(((k >> 8) * 8) + (lane >> 3)) * 8192 + (k & 255) * 32 + (lane & 7) * 4;
    f16x4 h1 = *(const f16x4*)(ehs + base);
    f16x4 h2 = *(const f16x4*)(ehs + EH_PLANE + base);
    float4 ev;
    ev.x = (float)h1[0] + (float)h2[0];
    ev.y = (float)h1[1] + (float)h2[1];
    ev.z = (float)h1[2] + (float)h2[2];
    ev.w = (float)h1[3] + (float)h2[3];
    *(float4*)&out_q[(size_t)n * DIM + lane * 4] = ev;
    float dx = ev.x - xv.x, dy = ev.y - xv.y, dz = ev.z - xv.z, dw = ev.w - xv.w;
    float s = dx * dx + dy * dy + dz * dz + dw * dw;
#pragma unroll
    for (int off = 32; off > 0; off >>= 1) s += __shfl_down(s, off, 64);
    float* dp = &dwT[(size_t)k * DIM + lane * 4];
    atomicAdd(dp + 0, xv.x);
    atomicAdd(dp + 1, xv.y);
    atomicAdd(dp + 2, xv.z);
    atomicAdd(dp + 3, xv.w);
    if (lane == 0) {
        atomicAdd(&counts[k], 1.0f);
        atomicAdd(&lossp[blockIdx.x & 255], s);
        out_idxf[n] = (float)k;
    }
}

__global__ void k_finalize(const float* __restrict__ counts, const float* __restrict__ lossp,
                           const float* __restrict__ ema_counter,
                           const float* __restrict__ ema_cluster,
                           float* __restrict__ cnorm, float* __restrict__ scal,
                           float* __restrict__ out)
{
    __shared__ float red[256];
    int t = threadIdx.x;
    float ls = lossp[t];
    float ent = 0.0f, casum = 0.0f;
    float ca[16];
#pragma unroll
    for (int j = 0; j < 16; ++j) {
        int k = j * 256 + t;
        float c = counts[k];
        float p = c * (1.0f / 32768.0f);
        ent += p * logf(p + 1e-10f);
        ca[j] = ema_cluster[k] * 0.99f + c * 0.01f;   // cluster_hidden
        casum += ca[j];
    }
    red[t] = ls; __syncthreads();
    for (int o = 128; o > 0; o >>= 1) { if (t < o) red[t] += red[t + o]; __syncthreads(); }
    float loss_tot = red[0]; __syncthreads();
    red[t] = ent; __syncthreads();
    for (int o = 128; o > 0; o >>= 1) { if (t < o) red[t] += red[t + o]; __syncthreads(); }
    float ent_tot = red[0]; __syncthreads();
    red[t] = casum; __syncthreads();
    for (int o = 128; o > 0; o >>= 1) { if (t < o) red[t] += red[t + o]; __syncthreads(); }
    float casum_tot = red[0]; __syncthreads();

    float bias = 1.0f - powf(0.99f, ema_counter[0] + 1.0f);
    float n = casum_tot / bias;                 // sum(cluster_avg)
    float inv = n / (n + 4096.0f * 1e-5f);
#pragma unroll
    for (int j = 0; j < 16; ++j) {
        int k = j * 256 + t;
        cnorm[k] = (ca[j] / bias + 1e-5f) * inv;
    }
    if (t == 0) {
        out[OUT_LOSS] = 1.25f * loss_tot * (1.0f / (32768.0f * 256.0f));
        out[OUT_PERP] = expf(-ent_tot);
        scal[0] = bias;
    }
}

// new_embeddings[d][k] = (ema_dw*DECAY + dwT^T*(1-DECAY))/bias / cnorm[k]
__global__ void k_newemb(const float* __restrict__ dwT, const float* __restrict__ ema_dw,
                         const float* __restrict__ cnorm, const float* __restrict__ scal,
                         float* __restrict__ out_emb)
{
    __shared__ float tile[32][33];
    int t = threadIdx.x;
    int tx = t & 31, iy = t >> 5;
    int k0 = blockIdx.x * 32, d0 = blockIdx.y * 32;
#pragma unroll
    for (int j = 0; j < 4; ++j)
        tile[iy + 8 * j][tx] = dwT[(size_t)(k0 + iy + 8 * j) * DIM + d0 + tx];
    __syncthreads();
    float inv_bias = 1.0f / scal[0];
    float cn = cnorm[k0 + tx];
#pragma unroll
    for (int j = 0; j < 4; ++j) {
        int d = d0 + iy + 8 * j;
        float dwv = tile[tx][iy + 8 * j];
        float hid = ema_dw[(size_t)d * KCODE + k0 + tx] * 0.99f + dwv * 0.01f;
        out_emb[(size_t)d * KCODE + k0 + tx] = hid * inv_bias / cn;
    }
}

extern "C" void kernel_launch(void* const* d_in, const int* in_sizes, int n_in,
                              void* d_out, int out_size, void* d_ws, size_t ws_size,
                              hipStream_t stream)
{
    const float* x           = (const float*)d_in[0];
    const float* emb         = (const float*)d_in[1];
    const float* ema_counter = (const float*)d_in[2];
    const float* ema_cluster = (const float*)d_in[3];
    const float* ema_dw      = (const float*)d_in[4];
    float* out = (float*)d_out;
    float* ws  = (float*)d_ws;

    float* e2     = ws + WS_E2;
    float* counts = ws + WS_COUNTS;
    float* lossp  = ws + WS_LOSSP;
    float* scal   = ws + WS_SCAL;
    float* cnorm  = ws + WS_CNORM;
    int*   idxw   = (int*)(ws + WS_IDX);
    unsigned short* ehs = (unsigned short*)(ws + WS_EHS);
    float* dwT    = ws + WS_DWT;
    unsigned short* xh = (unsigned short*)(out + OUT_Q);  // scratch, overwritten by k_gather

    hipMemsetAsync(e2, 0, (size_t)WS_CNORM * sizeof(float), stream);
    hipMemsetAsync(dwT, 0, (size_t)KCODE * DIM * sizeof(float), stream);

    k_e2<<<dim3(16, 8), 256, 0, stream>>>(emb, e2);
    k_split_e<<<dim3(128, 8), 256, 0, stream>>>(emb, ehs);
    k_split_x<<<4096, 256, 0, stream>>>(x, xh);
    k_argmin<<<512, 256, 0, stream>>>(xh, ehs, e2, idxw);
    k_gather<<<8192, 256, 0, stream>>>(x, ehs, idxw, out + OUT_Q, out + OUT_IDX,
                                       counts, dwT, lossp);
    k_finalize<<<1, 256, 0, stream>>>(counts, lossp, ema_counter, ema_cluster,
                                      cnorm, scal, out);
    k_newemb<<<dim3(128, 8), 256, 0, stream>>>(dwT, ema_dw, cnorm, scal, out + OUT_EMB);
}

// Round 2
// 450.890 us; speedup vs baseline: 1.3909x; 1.3663x over previous
//
#include <hip/hip_runtime.h>
#include <math.h>

#define N_TOK 32768
#define DIM   256
#define KCODE 4096

// ---- workspace layout (float offsets) ----
#define WS_E2      0                      // [4096]
#define WS_COUNTS  4096                   // [4096]
#define WS_LOSSP   8192                   // [256]
#define WS_SCAL    8448                   // [64]  scal[0]=bias
#define WS_CNORM   8512                   // [4096]
#define WS_IDX     12608                  // int [32768]
#define WS_EHS     307520                 // fp16 planes [2][16][8][256][32] = 4 MB
#define WS_DWT     1356096                // dwT [4096*256]
#define WS_CARRYV  2404672                // float [32768] running best value
#define WS_CARRYI  2437440                // int   [32768] running best index

// ---- output layout (float offsets) ----
#define OUT_Q      0
#define OUT_LOSS   8388608
#define OUT_PERP   8388609
#define OUT_IDX    8388610
#define OUT_EMB    8421378

#define EH_PLANE   1048576                // halves per eh plane
#define XH_PLANE   8388608                // halves per xh plane

typedef _Float16 f16x8 __attribute__((ext_vector_type(8)));
typedef _Float16 f16x4 __attribute__((ext_vector_type(4)));
typedef float    f32x4 __attribute__((ext_vector_type(4)));

// ||e_k||^2, partials over d with atomics (e2 pre-zeroed)
__global__ void k_e2(const float* __restrict__ emb, float* __restrict__ e2)
{
    int k  = blockIdx.x * 256 + threadIdx.x;
    int d0 = blockIdx.y * 32;
    float s = 0.0f;
#pragma unroll 8
    for (int d = 0; d < 32; ++d) {
        float v = emb[(size_t)(d0 + d) * KCODE + k];
        s += v * v;
    }
    atomicAdd(&e2[k], s);
}

// x [N][D] -> split fp16 planes xh[2][N][D] (stored in d_out OUT_Q region)
__global__ void k_split_x(const float* __restrict__ x, unsigned short* __restrict__ xh)
{
    int i = (blockIdx.x * 256 + threadIdx.x) * 8;
    float4 f0 = *(const float4*)(x + i);
    float4 f1 = *(const float4*)(x + i + 4);
    float fv[8] = {f0.x, f0.y, f0.z, f0.w, f1.x, f1.y, f1.z, f1.w};
    f16x8 h1, h2;
#pragma unroll
    for (int j = 0; j < 8; ++j) {
        _Float16 a = (_Float16)fv[j];
        h1[j] = a;
        h2[j] = (_Float16)(fv[j] - (float)a);
    }
    *(f16x8*)((_Float16*)xh + i)            = h1;
    *(f16x8*)((_Float16*)xh + XH_PLANE + i) = h2;
}

// emb [D][K] -> pre-tiled split planes ehs[p][ct][ks][code&255][d&31]
__global__ void k_split_e(const float* __restrict__ emb, unsigned short* __restrict__ ehs_)
{
    __shared__ float tile[32][33];
    _Float16* ehs = (_Float16*)ehs_;
    int t  = threadIdx.x;
    int tx = t & 31, iy = t >> 5;
    int k0 = blockIdx.x * 32, d0 = blockIdx.y * 32;
#pragma unroll
    for (int j = 0; j < 4; ++j)
        tile[iy + 8 * j][tx] = emb[(size_t)(d0 + iy + 8 * j) * KCODE + k0 + tx];
    __syncthreads();
    // tile[d_off][k_off]; this thread emits code = k0+tx, d = d0 + iy*4 .. +3
    int code = k0 + tx;
    size_t base = (size_t)(((code >> 8) * 8) + (d0 >> 5)) * 8192 + (code & 255) * 32 + iy * 4;
    f16x4 h1, h2;
#pragma unroll
    for (int j = 0; j < 4; ++j) {
        float v = tile[iy * 4 + j][tx];
        _Float16 a = (_Float16)v;
        h1[j] = a;
        h2[j] = (_Float16)(v - (float)a);
    }
    *(f16x4*)(ehs + base)            = h1;
    *(f16x4*)(ehs + EH_PLANE + base) = h2;
}

// Argmin over codes via fp16x2-split MFMA.
// Split into TWO dispatches over ct halves: per-dispatch B working set = 2 MB
// (half of one XCD's 4 MB L2) -> cyclic-scan thrash eliminated by capacity.
// Running (best,idx) carried across dispatches via carryV/carryI.
// A planes in LDS (nontemporal-loaded once, single barrier); B fragments loaded
// directly from global ehs (L2-resident), register double-buffered one ks-step
// ahead with a sched_barrier pinning the prefetch ahead of the MFMA cluster.
__global__ __launch_bounds__(256, 2)
void k_argmin(const unsigned short* __restrict__ xh_, const unsigned short* __restrict__ ehs_,
              const float* __restrict__ e2, int* __restrict__ idx_out,
              float* __restrict__ carryV, int* __restrict__ carryI,
              int ct0, int phase)
{
    __shared__ __align__(16) _Float16 Ah[2][64][256];   // 64 KB; XOR-swizzled 8-elem groups

    const _Float16* xh  = (const _Float16*)xh_;
    const _Float16* ehs = (const _Float16*)ehs_;

    const int t    = threadIdx.x;
    const int lane = t & 63, w = t >> 6;
    const int lo   = lane & 15, q = lane >> 4;
    const int row0 = blockIdx.x * 64;

    // ---- prologue: stage A planes from xh (rows m and m+32), non-temporal ----
    {
        int m = t >> 3, kb = (t & 7) * 32;
#pragma unroll
        for (int p = 0; p < 2; ++p)
#pragma unroll
            for (int rr = 0; rr < 2; ++rr) {
                int mm = m + 32 * rr;
                const _Float16* src = xh + (size_t)p * XH_PLANE + (size_t)(row0 + mm) * DIM + kb;
#pragma unroll
                for (int g = 0; g < 4; ++g) {
                    f16x8 h = __builtin_nontemporal_load((const f16x8*)(src + g * 8));
                    int grp = ((kb >> 3) + g) ^ (mm & 7);
                    *(f16x8*)&Ah[p][mm][grp * 8] = h;
                }
            }
    }
    __syncthreads();   // the ONLY barrier before the epilogue

    float best[16];
    int   bidx[16];
#pragma unroll
    for (int s = 0; s < 16; ++s) { best[s] = 3.4e38f; bidx[s] = 0; }

    // B fragment base for this lane: code-within-tile crow = w*64 + nf*16 + lo, d-off q*8
    const _Float16* ehp1 = ehs + (size_t)(w * 64 + lo) * 32 + q * 8;
    const _Float16* ehp2 = ehp1 + EH_PLANE;

    // register double-buffer for B fragments; parity = ks&1 (ks fully unrolled
    // so all indices are compile-time -> stays in VGPRs, no scratch)
    f16x8 b1f[2][4], b2f[2][4];

    // prime: load B for so = ct0*8
    {
        const size_t so0 = (size_t)(ct0 * 8) * 8192;
#pragma unroll
        for (int nf = 0; nf < 4; ++nf) {
            b1f[0][nf] = *(const f16x8*)(ehp1 + so0 + nf * 512);
            b2f[0][nf] = *(const f16x8*)(ehp2 + so0 + nf * 512);
        }
    }

    for (int ct = ct0; ct < ct0 + 8; ++ct) {
        f32x4 acc[4][4];
#pragma unroll
        for (int mf = 0; mf < 4; ++mf)
#pragma unroll
            for (int nf = 0; nf < 4; ++nf) acc[mf][nf] = (f32x4)0.0f;

#pragma unroll
        for (int ks = 0; ks < 8; ++ks) {
            const int cur = ks & 1, nxt = cur ^ 1;
            const int so  = ct * 8 + ks;

            // ---- prefetch B for so+1 into the other parity buffer ----
            if (ks < 7 || ct < ct0 + 7) {
                const size_t po = (size_t)(so + 1) * 8192;
#pragma unroll
                for (int nf = 0; nf < 4; ++nf) {
                    b1f[nxt][nf] = *(const f16x8*)(ehp1 + po + nf * 512);
                    b2f[nxt][nf] = *(const f16x8*)(ehp2 + po + nf * 512);
                }
            }
            // pin the prefetch: nothing may be scheduled across this point,
            // so the loads above issue BEFORE the MFMA cluster below.
            __builtin_amdgcn_sched_barrier(0);

            // ---- A fragments via LDS (conflict-free b128 via XOR swizzle) ----
            const int agrp = ((ks * 4 + q) ^ (lo & 7)) * 8;
            f16x8 a1[4], a2[4];
#pragma unroll
            for (int mf = 0; mf < 4; ++mf)
                a2[mf] = *(const f16x8*)&Ah[1][mf * 16 + lo][agrp];
#pragma unroll
            for (int mf = 0; mf < 4; ++mf)
                a1[mf] = *(const f16x8*)&Ah[0][mf * 16 + lo][agrp];

            // ---- MFMA cluster on the CURRENT buffer (loaded last iteration) ----
            __builtin_amdgcn_s_setprio(1);
#pragma unroll
            for (int nf = 0; nf < 4; ++nf) {
#pragma unroll
                for (int mf = 0; mf < 4; ++mf) {
                    acc[mf][nf] = __builtin_amdgcn_mfma_f32_16x16x32_f16(a2[mf], b1f[cur][nf], acc[mf][nf], 0, 0, 0);
                    acc[mf][nf] = __builtin_amdgcn_mfma_f32_16x16x32_f16(a1[mf], b2f[cur][nf], acc[mf][nf], 0, 0, 0);
                    acc[mf][nf] = __builtin_amdgcn_mfma_f32_16x16x32_f16(a1[mf], b1f[cur][nf], acc[mf][nf], 0, 0, 0);
                }
            }
            __builtin_amdgcn_s_setprio(0);
        }

        // fold: dist = e2 - 2*score (x^2 row-constant dropped). codes ascending in ct,nf.
#pragma unroll
        for (int nf = 0; nf < 4; ++nf) {
            int cl = w * 64 + nf * 16 + lo;
            float e2v = e2[ct * 256 + cl];
#pragma unroll
            for (int mf = 0; mf < 4; ++mf)
#pragma unroll
                for (int r = 0; r < 4; ++r) {
                    float dist = fmaf(-2.0f, acc[mf][nf][r], e2v);
                    int s = mf * 4 + r;
                    if (dist < best[s]) { best[s] = dist; bidx[s] = ct * 256 + cl; }
                }
        }
    }

    // ---- final argmin reduction (scratch overlays Ah) ----
    __syncthreads();
    float* rv = (float*)&Ah[0][0][0];                 // [64 rows][64 slots]
    int*   ri = (int*)(((char*)&Ah[0][0][0]) + 16384);
#pragma unroll
    for (int s = 0; s < 16; ++s) {
        int row = (s >> 2) * 16 + q * 4 + (s & 3);    // mf*16 + q*4 + r
        rv[row * 64 + w * 16 + lo] = best[s];
        ri[row * 64 + w * 16 + lo] = bidx[s];
    }
    __syncthreads();
    if (t < 64) {
        float bv; int bi;
        if (phase) { bv = carryV[row0 + t]; bi = carryI[row0 + t]; }
        else       { bv = 3.4e38f; bi = 0x40000000; }
        // staggered scan start -> banks spread across t (was 64-way conflict)
        for (int jj = 0; jj < 64; ++jj) {
            int j = (jj + t) & 63;
            float v = rv[t * 64 + j];
            int  ii = ri[t * 64 + j];
            if (v < bv || (v == bv && ii < bi)) { bv = v; bi = ii; }
        }
        if (phase) idx_out[row0 + t] = bi;
        else { carryV[row0 + t] = bv; carryI[row0 + t] = bi; }
    }
}

// one wave per row: quantized copy (reconstructed from planes), loss, counts, dwT, idx
__global__ void k_gather(const float* __restrict__ x, const unsigned short* __restrict__ ehs_,
                         const int* __restrict__ idx, float* __restrict__ out_q,
                         float* __restrict__ out_idxf, float* __restrict__ counts,
                         float* __restrict__ dwT, float* __restrict__ lossp)
{
    const _Float16* ehs = (const _Float16*)ehs_;
    int t = threadIdx.x;
    int lane = t & 63, w = t >> 6;
    int n = blockIdx.x * 4 + w;
    int k = idx[n];
    float4 xv = *(const float4*)&x[(size_t)n * DIM + lane * 4];
    size_t base = (size_t)(((k >> 8) * 8) + (lane >> 3)) * 8192 + (k & 255) * 32 + (lane & 7) * 4;
    f16x4 h1 = *(const f16x4*)(ehs + base);
    f16x4 h2 = *(const f16x4*)(ehs + EH_PLANE + base);
    float4 ev;
    ev.x = (float)h1[0] + (float)h2[0];
    ev.y = (float)h1[1] + (float)h2[1];
    ev.z = (float)h1[2] + (float)h2[2];
    ev.w = (float)h1[3] + (float)h2[3];
    *(float4*)&out_q[(size_t)n * DIM + lane * 4] = ev;
    float dx = ev.x - xv.x, dy = ev.y - xv.y, dz = ev.z - xv.z, dw = ev.w - xv.w;
    float s = dx * dx + dy * dy + dz * dz + dw * dw;
#pragma unroll
    for (int off = 32; off > 0; off >>= 1) s += __shfl_down(s, off, 64);
    float* dp = &dwT[(size_t)k * DIM + lane * 4];
    atomicAdd(dp + 0, xv.x);
    atomicAdd(dp + 1, xv.y);
    atomicAdd(dp + 2, xv.z);
    atomicAdd(dp + 3, xv.w);
    if (lane == 0) {
        atomicAdd(&counts[k], 1.0f);
        atomicAdd(&lossp[blockIdx.x & 255], s);
        out_idxf[n] = (float)k;
    }
}

__global__ void k_finalize(const float* __restrict__ counts, const float* __restrict__ lossp,
                           const float* __restrict__ ema_counter,
                           const float* __restrict__ ema_cluster,
                           float* __restrict__ cnorm, float* __restrict__ scal,
                           float* __restrict__ out)
{
    __shared__ float red[256];
    int t = threadIdx.x;
    float ls = lossp[t];
    float ent = 0.0f, casum = 0.0f;
    float ca[16];
#pragma unroll
    for (int j = 0; j < 16; ++j) {
        int k = j * 256 + t;
        float c = counts[k];
        float p = c * (1.0f / 32768.0f);
        ent += p * logf(p + 1e-10f);
        ca[j] = ema_cluster[k] * 0.99f + c * 0.01f;   // cluster_hidden
        casum += ca[j];
    }
    red[t] = ls; __syncthreads();
    for (int o = 128; o > 0; o >>= 1) { if (t < o) red[t] += red[t + o]; __syncthreads(); }
    float loss_tot = red[0]; __syncthreads();
    red[t] = ent; __syncthreads();
    for (int o = 128; o > 0; o >>= 1) { if (t < o) red[t] += red[t + o]; __syncthreads(); }
    float ent_tot = red[0]; __syncthreads();
    red[t] = casum; __syncthreads();
    for (int o = 128; o > 0; o >>= 1) { if (t < o) red[t] += red[t + o]; __syncthreads(); }
    float casum_tot = red[0]; __syncthreads();

    float bias = 1.0f - powf(0.99f, ema_counter[0] + 1.0f);
    float n = casum_tot / bias;                 // sum(cluster_avg)
    float inv = n / (n + 4096.0f * 1e-5f);
#pragma unroll
    for (int j = 0; j < 16; ++j) {
        int k = j * 256 + t;
        cnorm[k] = (ca[j] / bias + 1e-5f) * inv;
    }
    if (t == 0) {
        out[OUT_LOSS] = 1.25f * loss_tot * (1.0f / (32768.0f * 256.0f));
        out[OUT_PERP] = expf(-ent_tot);
        scal[0] = bias;
    }
}

// new_embeddings[d][k] = (ema_dw*DECAY + dwT^T*(1-DECAY))/bias / cnorm[k]
__global__ void k_newemb(const float* __restrict__ dwT, const float* __restrict__ ema_dw,
                         const float* __restrict__ cnorm, const float* __restrict__ scal,
                         float* __restrict__ out_emb)
{
    __shared__ float tile[32][33];
    int t = threadIdx.x;
    int tx = t & 31, iy = t >> 5;
    int k0 = blockIdx.x * 32, d0 = blockIdx.y * 32;
#pragma unroll
    for (int j = 0; j < 4; ++j)
        tile[iy + 8 * j][tx] = dwT[(size_t)(k0 + iy + 8 * j) * DIM + d0 + tx];
    __syncthreads();
    float inv_bias = 1.0f / scal[0];
    float cn = cnorm[k0 + tx];
#pragma unroll
    for (int j = 0; j < 4; ++j) {
        int d = d0 + iy + 8 * j;
        float dwv = tile[tx][iy + 8 * j];
        float hid = ema_dw[(size_t)d * KCODE + k0 + tx] * 0.99f + dwv * 0.01f;
        out_emb[(size_t)d * KCODE + k0 + tx] = hid * inv_bias / cn;
    }
}

extern "C" void kernel_launch(void* const* d_in, const int* in_sizes, int n_in,
                              void* d_out, int out_size, void* d_ws, size_t ws_size,
                              hipStream_t stream)
{
    const float* x           = (const float*)d_in[0];
    const float* emb         = (const float*)d_in[1];
    const float* ema_counter = (const float*)d_in[2];
    const float* ema_cluster = (const float*)d_in[3];
    const float* ema_dw      = (const float*)d_in[4];
    float* out = (float*)d_out;
    float* ws  = (float*)d_ws;

    float* e2     = ws + WS_E2;
    float* counts = ws + WS_COUNTS;
    float* lossp  = ws + WS_LOSSP;
    float* scal   = ws + WS_SCAL;
    float* cnorm  = ws + WS_CNORM;
    int*   idxw   = (int*)(ws + WS_IDX);
    unsigned short* ehs = (unsigned short*)(ws + WS_EHS);
    float* dwT    = ws + WS_DWT;
    float* carryV = ws + WS_CARRYV;
    int*   carryI = (int*)(ws + WS_CARRYI);
    unsigned short* xh = (unsigned short*)(out + OUT_Q);  // scratch, overwritten by k_gather

    hipMemsetAsync(e2, 0, (size_t)WS_CNORM * sizeof(float), stream);

    k_e2<<<dim3(16, 8), 256, 0, stream>>>(emb, e2);
    k_split_e<<<dim3(128, 8), 256, 0, stream>>>(emb, ehs);
    k_split_x<<<4096, 256, 0, stream>>>(x, xh);
    // two ct-half dispatches: each streams only 2 MB of ehs (fits L2 w/ headroom)
    k_argmin<<<512, 256, 0, stream>>>(xh, ehs, e2, idxw, carryV, carryI, 0, 0);
    k_argmin<<<512, 256, 0, stream>>>(xh, ehs, e2, idxw, carryV, carryI, 8, 1);
    // dwT memset AFTER argmin so 4 MB of dirty lines don't sit in L2 during the scan
    hipMemsetAsync(dwT, 0, (size_t)KCODE * DIM * sizeof(float), stream);
    k_gather<<<8192, 256, 0, stream>>>(x, ehs, idxw, out + OUT_Q, out + OUT_IDX,
                                       counts, dwT, lossp);
    k_finalize<<<1, 256, 0, stream>>>(counts, lossp, ema_counter, ema_cluster,
                                      cnorm, scal, out);
    k_newemb<<<dim3(128, 8), 256, 0, stream>>>(dwT, ema_dw, cnorm, scal, out + OUT_EMB);
}

// Round 3
// 363.328 us; speedup vs baseline: 1.7261x; 1.2410x over previous
//
#include <hip/hip_runtime.h>
#include <math.h>

#define N_TOK 32768
#define DIM   256
#define KCODE 4096

// ---- workspace layout (float offsets) ----
#define WS_E2      0                      // [4096]
#define WS_COUNTS  4096                   // [4096]
#define WS_LOSSP   8192                   // [256]
#define WS_SCAL    8448                   // [64]  scal[0]=bias
#define WS_CNORM   8512                   // [4096]
#define WS_IDX     12608                  // int [32768]
#define WS_EHS     307520                 // fp16 planes [2][16][8][256][32] = 4 MB
#define WS_DWT     1356096                // dwT [4096*256]
#define WS_CARRYV  2404672                // float [32768] carry best value / later rowlist
#define WS_CARRYI  2437440                // int   [32768] carry best index
#define WS_OFFS    2470208                // int [4096] bucket starts
#define WS_WOFF    2474304                // int [4096] scatter cursors

// ---- output layout (float offsets) ----
#define OUT_Q      0
#define OUT_LOSS   8388608
#define OUT_PERP   8388609
#define OUT_IDX    8388610
#define OUT_EMB    8421378

#define EH_PLANE   1048576                // halves per eh plane
#define XH_PLANE   8388608                // halves per xh plane

typedef _Float16 f16x8 __attribute__((ext_vector_type(8)));
typedef _Float16 f16x4 __attribute__((ext_vector_type(4)));
typedef float    f32x4 __attribute__((ext_vector_type(4)));

// ||e_k||^2, partials over d with atomics (e2 pre-zeroed)
__global__ void k_e2(const float* __restrict__ emb, float* __restrict__ e2)
{
    int k  = blockIdx.x * 256 + threadIdx.x;
    int d0 = blockIdx.y * 32;
    float s = 0.0f;
#pragma unroll 8
    for (int d = 0; d < 32; ++d) {
        float v = emb[(size_t)(d0 + d) * KCODE + k];
        s += v * v;
    }
    atomicAdd(&e2[k], s);
}

// x [N][D] -> split fp16 planes xh[2][N][D] (stored in d_out OUT_Q region)
__global__ void k_split_x(const float* __restrict__ x, unsigned short* __restrict__ xh)
{
    int i = (blockIdx.x * 256 + threadIdx.x) * 8;
    float4 f0 = *(const float4*)(x + i);
    float4 f1 = *(const float4*)(x + i + 4);
    float fv[8] = {f0.x, f0.y, f0.z, f0.w, f1.x, f1.y, f1.z, f1.w};
    f16x8 h1, h2;
#pragma unroll
    for (int j = 0; j < 8; ++j) {
        _Float16 a = (_Float16)fv[j];
        h1[j] = a;
        h2[j] = (_Float16)(fv[j] - (float)a);
    }
    *(f16x8*)((_Float16*)xh + i)            = h1;
    *(f16x8*)((_Float16*)xh + XH_PLANE + i) = h2;
}

// emb [D][K] -> pre-tiled split planes ehs[p][ct][ks][code&255][d&31]
__global__ void k_split_e(const float* __restrict__ emb, unsigned short* __restrict__ ehs_)
{
    __shared__ float tile[32][33];
    _Float16* ehs = (_Float16*)ehs_;
    int t  = threadIdx.x;
    int tx = t & 31, iy = t >> 5;
    int k0 = blockIdx.x * 32, d0 = blockIdx.y * 32;
#pragma unroll
    for (int j = 0; j < 4; ++j)
        tile[iy + 8 * j][tx] = emb[(size_t)(d0 + iy + 8 * j) * KCODE + k0 + tx];
    __syncthreads();
    int code = k0 + tx;
    size_t base = (size_t)(((code >> 8) * 8) + (d0 >> 5)) * 8192 + (code & 255) * 32 + iy * 4;
    f16x4 h1, h2;
#pragma unroll
    for (int j = 0; j < 4; ++j) {
        float v = tile[iy * 4 + j][tx];
        _Float16 a = (_Float16)v;
        h1[j] = a;
        h2[j] = (_Float16)(v - (float)a);
    }
    *(f16x4*)(ehs + base)            = h1;
    *(f16x4*)(ehs + EH_PLANE + base) = h2;
}

// Argmin over codes via fp16x2-split MFMA, two ct-half dispatches (2 MB L2 WS each).
// Phase 1 epilogue also emits idx float copy + code histogram (counts).
__global__ __launch_bounds__(256, 2)
void k_argmin(const unsigned short* __restrict__ xh_, const unsigned short* __restrict__ ehs_,
              const float* __restrict__ e2, int* __restrict__ idx_out,
              float* __restrict__ carryV, int* __restrict__ carryI,
              float* __restrict__ out_idxf, float* __restrict__ counts,
              int ct0, int phase)
{
    __shared__ __align__(16) _Float16 Ah[2][64][256];   // 64 KB; XOR-swizzled 8-elem groups

    const _Float16* xh  = (const _Float16*)xh_;
    const _Float16* ehs = (const _Float16*)ehs_;

    const int t    = threadIdx.x;
    const int lane = t & 63, w = t >> 6;
    const int lo   = lane & 15, q = lane >> 4;
    const int row0 = blockIdx.x * 64;

    // ---- prologue: stage A planes from xh (rows m and m+32), non-temporal ----
    {
        int m = t >> 3, kb = (t & 7) * 32;
#pragma unroll
        for (int p = 0; p < 2; ++p)
#pragma unroll
            for (int rr = 0; rr < 2; ++rr) {
                int mm = m + 32 * rr;
                const _Float16* src = xh + (size_t)p * XH_PLANE + (size_t)(row0 + mm) * DIM + kb;
#pragma unroll
                for (int g = 0; g < 4; ++g) {
                    f16x8 h = __builtin_nontemporal_load((const f16x8*)(src + g * 8));
                    int grp = ((kb >> 3) + g) ^ (mm & 7);
                    *(f16x8*)&Ah[p][mm][grp * 8] = h;
                }
            }
    }
    __syncthreads();   // the ONLY barrier before the epilogue

    float best[16];
    int   bidx[16];
#pragma unroll
    for (int s = 0; s < 16; ++s) { best[s] = 3.4e38f; bidx[s] = 0; }

    const _Float16* ehp1 = ehs + (size_t)(w * 64 + lo) * 32 + q * 8;
    const _Float16* ehp2 = ehp1 + EH_PLANE;

    f16x8 b1f[2][4], b2f[2][4];
    {
        const size_t so0 = (size_t)(ct0 * 8) * 8192;
#pragma unroll
        for (int nf = 0; nf < 4; ++nf) {
            b1f[0][nf] = *(const f16x8*)(ehp1 + so0 + nf * 512);
            b2f[0][nf] = *(const f16x8*)(ehp2 + so0 + nf * 512);
        }
    }

    for (int ct = ct0; ct < ct0 + 8; ++ct) {
        f32x4 acc[4][4];
#pragma unroll
        for (int mf = 0; mf < 4; ++mf)
#pragma unroll
            for (int nf = 0; nf < 4; ++nf) acc[mf][nf] = (f32x4)0.0f;

#pragma unroll
        for (int ks = 0; ks < 8; ++ks) {
            const int cur = ks & 1, nxt = cur ^ 1;
            const int so  = ct * 8 + ks;

            if (ks < 7 || ct < ct0 + 7) {
                const size_t po = (size_t)(so + 1) * 8192;
#pragma unroll
                for (int nf = 0; nf < 4; ++nf) {
                    b1f[nxt][nf] = *(const f16x8*)(ehp1 + po + nf * 512);
                    b2f[nxt][nf] = *(const f16x8*)(ehp2 + po + nf * 512);
                }
            }
            __builtin_amdgcn_sched_barrier(0);

            const int agrp = ((ks * 4 + q) ^ (lo & 7)) * 8;
            f16x8 a1[4], a2[4];
#pragma unroll
            for (int mf = 0; mf < 4; ++mf)
                a2[mf] = *(const f16x8*)&Ah[1][mf * 16 + lo][agrp];
#pragma unroll
            for (int mf = 0; mf < 4; ++mf)
                a1[mf] = *(const f16x8*)&Ah[0][mf * 16 + lo][agrp];

            __builtin_amdgcn_s_setprio(1);
#pragma unroll
            for (int nf = 0; nf < 4; ++nf) {
#pragma unroll
                for (int mf = 0; mf < 4; ++mf) {
                    acc[mf][nf] = __builtin_amdgcn_mfma_f32_16x16x32_f16(a2[mf], b1f[cur][nf], acc[mf][nf], 0, 0, 0);
                    acc[mf][nf] = __builtin_amdgcn_mfma_f32_16x16x32_f16(a1[mf], b2f[cur][nf], acc[mf][nf], 0, 0, 0);
                    acc[mf][nf] = __builtin_amdgcn_mfma_f32_16x16x32_f16(a1[mf], b1f[cur][nf], acc[mf][nf], 0, 0, 0);
                }
            }
            __builtin_amdgcn_s_setprio(0);
        }

#pragma unroll
        for (int nf = 0; nf < 4; ++nf) {
            int cl = w * 64 + nf * 16 + lo;
            float e2v = e2[ct * 256 + cl];
#pragma unroll
            for (int mf = 0; mf < 4; ++mf)
#pragma unroll
                for (int r = 0; r < 4; ++r) {
                    float dist = fmaf(-2.0f, acc[mf][nf][r], e2v);
                    int s = mf * 4 + r;
                    if (dist < best[s]) { best[s] = dist; bidx[s] = ct * 256 + cl; }
                }
        }
    }

    // ---- final argmin reduction (scratch overlays Ah) ----
    __syncthreads();
    float* rv = (float*)&Ah[0][0][0];                 // [64 rows][64 slots]
    int*   ri = (int*)(((char*)&Ah[0][0][0]) + 16384);
#pragma unroll
    for (int s = 0; s < 16; ++s) {
        int row = (s >> 2) * 16 + q * 4 + (s & 3);    // mf*16 + q*4 + r
        rv[row * 64 + w * 16 + lo] = best[s];
        ri[row * 64 + w * 16 + lo] = bidx[s];
    }
    __syncthreads();
    if (t < 64) {
        float bv; int bi;
        if (phase) { bv = carryV[row0 + t]; bi = carryI[row0 + t]; }
        else       { bv = 3.4e38f; bi = 0x40000000; }
        for (int jj = 0; jj < 64; ++jj) {
            int j = (jj + t) & 63;
            float v = rv[t * 64 + j];
            int  ii = ri[t * 64 + j];
            if (v < bv || (v == bv && ii < bi)) { bv = v; bi = ii; }
        }
        if (phase) {
            idx_out[row0 + t] = bi;
            out_idxf[row0 + t] = (float)bi;
            atomicAdd(&counts[bi], 1.0f);
        } else {
            carryV[row0 + t] = bv; carryI[row0 + t] = bi;
        }
    }
}

// exclusive prefix sum over counts[4096] -> offs, woff (one block, 256 threads x 16)
__global__ void k_scan(const float* __restrict__ counts, int* __restrict__ offs,
                       int* __restrict__ woff)
{
    __shared__ int ps[256];
    int t = threadIdx.x;
    int local[16];
    int s = 0;
#pragma unroll
    for (int j = 0; j < 16; ++j) {
        local[j] = s;
        s += (int)counts[t * 16 + j];
    }
    ps[t] = s;
    __syncthreads();
    for (int off = 1; off < 256; off <<= 1) {
        int v = (t >= off) ? ps[t - off] : 0;
        __syncthreads();
        ps[t] += v;
        __syncthreads();
    }
    int base = (t > 0) ? ps[t - 1] : 0;
#pragma unroll
    for (int j = 0; j < 16; ++j) {
        int o = base + local[j];
        offs[t * 16 + j] = o;
        woff[t * 16 + j] = o;
    }
}

// rowlist[pos] = n, grouped by code (counting-sort scatter)
__global__ void k_scatter(const int* __restrict__ idx, int* __restrict__ woff,
                          int* __restrict__ rowlist)
{
    int n = blockIdx.x * 256 + threadIdx.x;
    int k = idx[n];
    int pos = atomicAdd(&woff[k], 1);
    rowlist[pos] = n;
}

// dwT[k][d] = sum of x rows assigned to code k — one block per code, NO atomics
__global__ void k_dw(const float* __restrict__ x, const int* __restrict__ rowlist,
                     const int* __restrict__ offs, const float* __restrict__ counts,
                     float* __restrict__ dwT)
{
    __shared__ float red[4][256];
    int k = blockIdx.x;
    int t = threadIdx.x;
    int lane = t & 63, w = t >> 6;
    int start = offs[k];
    int cnt   = (int)counts[k];
    float4 acc = {0.0f, 0.0f, 0.0f, 0.0f};
    int j = w;
    for (; j + 4 < cnt; j += 8) {
        int n0 = rowlist[start + j];
        int n1 = rowlist[start + j + 4];
        float4 v0 = *(const float4*)&x[(size_t)n0 * DIM + lane * 4];
        float4 v1 = *(const float4*)&x[(size_t)n1 * DIM + lane * 4];
        acc.x += v0.x + v1.x; acc.y += v0.y + v1.y;
        acc.z += v0.z + v1.z; acc.w += v0.w + v1.w;
    }
    if (j < cnt) {
        int n0 = rowlist[start + j];
        float4 v0 = *(const float4*)&x[(size_t)n0 * DIM + lane * 4];
        acc.x += v0.x; acc.y += v0.y; acc.z += v0.z; acc.w += v0.w;
    }
    *(float4*)&red[w][lane * 4] = acc;
    __syncthreads();
    float s = red[0][t] + red[1][t] + red[2][t] + red[3][t];
    dwT[(size_t)k * DIM + t] = s;
}

// one wave per row: quantized copy (reconstructed from planes) + loss partial
__global__ void k_gather(const float* __restrict__ x, const unsigned short* __restrict__ ehs_,
                         const int* __restrict__ idx, float* __restrict__ out_q,
                         float* __restrict__ lossp)
{
    const _Float16* ehs = (const _Float16*)ehs_;
    int t = threadIdx.x;
    int lane = t & 63, w = t >> 6;
    int n = blockIdx.x * 4 + w;
    int k = idx[n];
    float4 xv = *(const float4*)&x[(size_t)n * DIM + lane * 4];
    size_t base = (size_t)(((k >> 8) * 8) + (lane >> 3)) * 8192 + (k & 255) * 32 + (lane & 7) * 4;
    f16x4 h1 = *(const f16x4*)(ehs + base);
    f16x4 h2 = *(const f16x4*)(ehs + EH_PLANE + base);
    float4 ev;
    ev.x = (float)h1[0] + (float)h2[0];
    ev.y = (float)h1[1] + (float)h2[1];
    ev.z = (float)h1[2] + (float)h2[2];
    ev.w = (float)h1[3] + (float)h2[3];
    *(float4*)&out_q[(size_t)n * DIM + lane * 4] = ev;
    float dx = ev.x - xv.x, dy = ev.y - xv.y, dz = ev.z - xv.z, dw = ev.w - xv.w;
    float s = dx * dx + dy * dy + dz * dz + dw * dw;
#pragma unroll
    for (int off = 32; off > 0; off >>= 1) s += __shfl_down(s, off, 64);
    if (lane == 0) atomicAdd(&lossp[blockIdx.x & 255], s);
}

__global__ void k_finalize(const float* __restrict__ counts, const float* __restrict__ lossp,
                           const float* __restrict__ ema_counter,
                           const float* __restrict__ ema_cluster,
                           float* __restrict__ cnorm, float* __restrict__ scal,
                           float* __restrict__ out)
{
    __shared__ float red[256];
    int t = threadIdx.x;
    float ls = lossp[t];
    float ent = 0.0f, casum = 0.0f;
    float ca[16];
#pragma unroll
    for (int j = 0; j < 16; ++j) {
        int k = j * 256 + t;
        float c = counts[k];
        float p = c * (1.0f / 32768.0f);
        ent += p * logf(p + 1e-10f);
        ca[j] = ema_cluster[k] * 0.99f + c * 0.01f;   // cluster_hidden
        casum += ca[j];
    }
    red[t] = ls; __syncthreads();
    for (int o = 128; o > 0; o >>= 1) { if (t < o) red[t] += red[t + o]; __syncthreads(); }
    float loss_tot = red[0]; __syncthreads();
    red[t] = ent; __syncthreads();
    for (int o = 128; o > 0; o >>= 1) { if (t < o) red[t] += red[t + o]; __syncthreads(); }
    float ent_tot = red[0]; __syncthreads();
    red[t] = casum; __syncthreads();
    for (int o = 128; o > 0; o >>= 1) { if (t < o) red[t] += red[t + o]; __syncthreads(); }
    float casum_tot = red[0]; __syncthreads();

    float bias = 1.0f - powf(0.99f, ema_counter[0] + 1.0f);
    float n = casum_tot / bias;                 // sum(cluster_avg)
    float inv = n / (n + 4096.0f * 1e-5f);
#pragma unroll
    for (int j = 0; j < 16; ++j) {
        int k = j * 256 + t;
        cnorm[k] = (ca[j] / bias + 1e-5f) * inv;
    }
    if (t == 0) {
        out[OUT_LOSS] = 1.25f * loss_tot * (1.0f / (32768.0f * 256.0f));
        out[OUT_PERP] = expf(-ent_tot);
        scal[0] = bias;
    }
}

// new_embeddings[d][k] = (ema_dw*DECAY + dwT^T*(1-DECAY))/bias / cnorm[k]
__global__ void k_newemb(const float* __restrict__ dwT, const float* __restrict__ ema_dw,
                         const float* __restrict__ cnorm, const float* __restrict__ scal,
                         float* __restrict__ out_emb)
{
    __shared__ float tile[32][33];
    int t = threadIdx.x;
    int tx = t & 31, iy = t >> 5;
    int k0 = blockIdx.x * 32, d0 = blockIdx.y * 32;
#pragma unroll
    for (int j = 0; j < 4; ++j)
        tile[iy + 8 * j][tx] = dwT[(size_t)(k0 + iy + 8 * j) * DIM + d0 + tx];
    __syncthreads();
    float inv_bias = 1.0f / scal[0];
    float cn = cnorm[k0 + tx];
#pragma unroll
    for (int j = 0; j < 4; ++j) {
        int d = d0 + iy + 8 * j;
        float dwv = tile[tx][iy + 8 * j];
        float hid = ema_dw[(size_t)d * KCODE + k0 + tx] * 0.99f + dwv * 0.01f;
        out_emb[(size_t)d * KCODE + k0 + tx] = hid * inv_bias / cn;
    }
}

extern "C" void kernel_launch(void* const* d_in, const int* in_sizes, int n_in,
                              void* d_out, int out_size, void* d_ws, size_t ws_size,
                              hipStream_t stream)
{
    const float* x           = (const float*)d_in[0];
    const float* emb         = (const float*)d_in[1];
    const float* ema_counter = (const float*)d_in[2];
    const float* ema_cluster = (const float*)d_in[3];
    const float* ema_dw      = (const float*)d_in[4];
    float* out = (float*)d_out;
    float* ws  = (float*)d_ws;

    float* e2     = ws + WS_E2;
    float* counts = ws + WS_COUNTS;
    float* lossp  = ws + WS_LOSSP;
    float* scal   = ws + WS_SCAL;
    float* cnorm  = ws + WS_CNORM;
    int*   idxw   = (int*)(ws + WS_IDX);
    unsigned short* ehs = (unsigned short*)(ws + WS_EHS);
    float* dwT    = ws + WS_DWT;
    float* carryV = ws + WS_CARRYV;
    int*   carryI = (int*)(ws + WS_CARRYI);
    int*   rowlist= (int*)(ws + WS_CARRYV);   // overlays carryV (dead after argmin B)
    int*   offs   = (int*)(ws + WS_OFFS);
    int*   woff   = (int*)(ws + WS_WOFF);
    unsigned short* xh = (unsigned short*)(out + OUT_Q);  // scratch, overwritten by k_gather

    hipMemsetAsync(e2, 0, (size_t)WS_CNORM * sizeof(float), stream);  // zeros e2+counts+lossp+scal

    k_e2<<<dim3(16, 8), 256, 0, stream>>>(emb, e2);
    k_split_e<<<dim3(128, 8), 256, 0, stream>>>(emb, ehs);
    k_split_x<<<4096, 256, 0, stream>>>(x, xh);
    // two ct-half dispatches: each streams only 2 MB of ehs (fits L2 w/ headroom)
    k_argmin<<<512, 256, 0, stream>>>(xh, ehs, e2, idxw, carryV, carryI,
                                      out + OUT_IDX, counts, 0, 0);
    k_argmin<<<512, 256, 0, stream>>>(xh, ehs, e2, idxw, carryV, carryI,
                                      out + OUT_IDX, counts, 8, 1);
    // quantized output + loss (no atomic scatter-add anymore)
    k_gather<<<8192, 256, 0, stream>>>(x, ehs, idxw, out + OUT_Q, lossp);
    // counting-sort dw reduction: scan -> scatter -> per-code sum (atomic-free dwT)
    k_scan<<<1, 256, 0, stream>>>(counts, offs, woff);
    k_scatter<<<128, 256, 0, stream>>>(idxw, woff, rowlist);
    k_dw<<<4096, 256, 0, stream>>>(x, rowlist, offs, counts, dwT);
    k_finalize<<<1, 256, 0, stream>>>(counts, lossp, ema_counter, ema_cluster,
                                      cnorm, scal, out);
    k_newemb<<<dim3(128, 8), 256, 0, stream>>>(dwT, ema_dw, cnorm, scal, out + OUT_EMB);
}